// Round 4
// baseline (812.913 us; speedup 1.0000x reference)
//
#include <hip/hip_runtime.h>
#include <hip/hip_bf16.h>

typedef __attribute__((ext_vector_type(8))) short short8;
typedef __attribute__((ext_vector_type(4))) float f32x4;

#define DEVI static __device__ __forceinline__

constexpr int HID = 1024;
constexpr int BB = 4, LL = 4096;
constexpr int MROWS = BB * LL;   // 16384
constexpr int FF = 4 * HID;      // 4096
constexpr int NCH = 64, TCH = 64;  // scan chunking

// ---------------- ws layout (bytes) ----------------
// bf16 pool: emb + all weights
constexpr size_t ELN_EMB = 0;                 // 16M elems
constexpr size_t ELN_WA  = 16777216;
constexpr size_t ELN_WB  = ELN_WA + 1048576;
constexpr size_t ELN_WO  = ELN_WB + 1048576;
constexpr size_t ELN_CW  = ELN_WO + 1048576;
constexpr size_t ELN_F1  = ELN_CW + 1048576;
constexpr size_t ELN_F2  = ELN_F1 + 4194304;
constexpr size_t ELN_PW  = ELN_F2 + 4194304;
constexpr size_t ELN_END = ELN_PW + 1048576;  // 30,408,704 elems
constexpr size_t POOL_BYTES = ELN_END * 2;    // 60,817,408 B

constexpr size_t REG = 33554432;              // 32MB per activation region (16M bf16)
constexpr size_t OFF_U  = POOL_BYTES;          // u bf16
constexpr size_t OFF_AZ = OFF_U  + REG;        // a, later z, later ffn(lo)
constexpr size_t OFF_W2 = OFF_AZ + REG;        // w, later ffn(hi)
constexpr size_t OFF_H2 = OFF_W2 + REG;        // h, later v
constexpr size_t OFF_B2 = OFF_H2 + REG;        // b
constexpr size_t OFF_AGG = OFF_B2 + REG;       // scan aggregates (3x 1MB f32)
constexpr size_t AG_ELEMS = (size_t)BB * NCH * HID;  // 262144
constexpr size_t WS_NEEDED = OFF_AGG + AG_ELEMS * 4 * 3;  // ~231.7MB

// ---------------- helpers ----------------
DEVI unsigned short f2b(float x) {            // f32 -> bf16 RNE
  unsigned u = __float_as_uint(x);
  return (unsigned short)((u + 0x7fffu + ((u >> 16) & 1u)) >> 16);
}
DEVI float b2f(unsigned short u) { return __uint_as_float((unsigned)u << 16); }

// ---------------- f32 -> bf16 conversion of emb + all weights ----------------
constexpr long CH_EMB = 16777216 / 8;
constexpr long CH_W   = 1048576 / 8;
constexpr long CH_F   = 4194304 / 8;
constexpr long SEG1 = CH_EMB;
constexpr long SEG2 = SEG1 + CH_W;
constexpr long SEG3 = SEG2 + CH_W;
constexpr long SEG4 = SEG3 + CH_W;
constexpr long SEG5 = SEG4 + CH_W;
constexpr long SEG6 = SEG5 + CH_F;
constexpr long SEG7 = SEG6 + CH_F;
constexpr long SEG8 = SEG7 + CH_W;

__global__ __launch_bounds__(256) void convert_all(
    const float* __restrict__ emb, const float* __restrict__ wa,
    const float* __restrict__ wb,  const float* __restrict__ wo,
    const float* __restrict__ cw,  const float* __restrict__ f1,
    const float* __restrict__ f2,  const float* __restrict__ pw,
    unsigned short* __restrict__ dst) {
  const long stride = (long)gridDim.x * blockDim.x;
  for (long ck = (long)blockIdx.x * blockDim.x + threadIdx.x; ck < SEG8; ck += stride) {
    const float* s; size_t d;
    if (ck < SEG1)      { s = emb + (size_t)ck * 8;        d = ELN_EMB + (size_t)ck * 8; }
    else if (ck < SEG2) { s = wa + (size_t)(ck-SEG1) * 8;  d = ELN_WA + (size_t)(ck-SEG1) * 8; }
    else if (ck < SEG3) { s = wb + (size_t)(ck-SEG2) * 8;  d = ELN_WB + (size_t)(ck-SEG2) * 8; }
    else if (ck < SEG4) { s = wo + (size_t)(ck-SEG3) * 8;  d = ELN_WO + (size_t)(ck-SEG3) * 8; }
    else if (ck < SEG5) { s = cw + (size_t)(ck-SEG4) * 8;  d = ELN_CW + (size_t)(ck-SEG4) * 8; }
    else if (ck < SEG6) { s = f1 + (size_t)(ck-SEG5) * 8;  d = ELN_F1 + (size_t)(ck-SEG5) * 8; }
    else if (ck < SEG7) { s = f2 + (size_t)(ck-SEG6) * 8;  d = ELN_F2 + (size_t)(ck-SEG6) * 8; }
    else                { s = pw + (size_t)(ck-SEG7) * 8;  d = ELN_PW + (size_t)(ck-SEG7) * 8; }
    float4 x = *(const float4*)s;
    float4 y = *(const float4*)(s + 4);
    short8 o;
    o[0]=(short)f2b(x.x); o[1]=(short)f2b(x.y); o[2]=(short)f2b(x.z); o[3]=(short)f2b(x.w);
    o[4]=(short)f2b(y.x); o[5]=(short)f2b(y.y); o[6]=(short)f2b(y.z); o[7]=(short)f2b(y.w);
    *(short8*)(dst + d) = o;
  }
}

// ---------------- GEMM: C = A(MxK) * W(NxK)^T, 128x128 tile, reg-staged LDS ----
// EPI: 0 tanh->bf16 | 1 +bias->bf16 | 2 z=hw*(acc+bias+add)->bf16
//      3 gelu->bf16 | 4 acc+bias+add->bf16 | 5 +bias->f32
template <int EPI>
__global__ __launch_bounds__(256) void gemm_bt(
    const unsigned short* __restrict__ A, const unsigned short* __restrict__ Bw,
    int K, int N,
    const float* __restrict__ bias, const unsigned short* __restrict__ addB,
    const float* __restrict__ hw,
    float* __restrict__ outF, unsigned short* __restrict__ outB) {
  __shared__ alignas(16) unsigned short ldsA[128 * 32];
  __shared__ alignas(16) unsigned short ldsB[128 * 32];
  const int tid = threadIdx.x;
  const int lane = tid & 63, wave = tid >> 6;
  const int wr = wave >> 1, wc = wave & 1;           // wave -> 64x64 subtile
  const int arow0 = blockIdx.x * 128, bcol0 = blockIdx.y * 128;
  f32x4 acc[4][4] = {};
  const int fm = lane & 15, fk = (lane >> 4) * 8;    // fragment coords
  const int skb = (tid & 3) * 8;                     // staging coords (row = tid>>2)
  const unsigned short* Ag = A + (size_t)(arow0 + (tid >> 2)) * K + skb;
  const unsigned short* Bg = Bw + (size_t)(bcol0 + (tid >> 2)) * K + skb;
  const size_t rowskip = (size_t)64 * K;
  for (int k0 = 0; k0 < K; k0 += 32) {
    short8 va0 = *(const short8*)(Ag + k0);
    short8 va1 = *(const short8*)(Ag + k0 + rowskip);
    short8 vb0 = *(const short8*)(Bg + k0);
    short8 vb1 = *(const short8*)(Bg + k0 + rowskip);
    __syncthreads();                      // prior reads of LDS complete
    *(short8*)&ldsA[tid * 8]        = va0;
    *(short8*)&ldsA[2048 + tid * 8] = va1;
    *(short8*)&ldsB[tid * 8]        = vb0;
    *(short8*)&ldsB[2048 + tid * 8] = vb1;
    __syncthreads();                      // writes visible
    short8 af[4], bfr[4];
#pragma unroll
    for (int i = 0; i < 4; ++i) {
      af[i]  = *(const short8*)&ldsA[(wr * 64 + i * 16 + fm) * 32 + fk];
      bfr[i] = *(const short8*)&ldsB[(wc * 64 + i * 16 + fm) * 32 + fk];
    }
#pragma unroll
    for (int i = 0; i < 4; ++i)
#pragma unroll
      for (int j = 0; j < 4; ++j)
        acc[i][j] = __builtin_amdgcn_mfma_f32_16x16x32_bf16(af[i], bfr[j], acc[i][j], 0, 0, 0);
  }
  // epilogue: D row = (lane>>4)*4 + reg, col = lane&15  [m89-verified]
  const int m0 = arow0 + wr * 64, n0 = bcol0 + wc * 64;
  const int crow = (lane >> 4) * 4, ccol = lane & 15;
#pragma unroll
  for (int i = 0; i < 4; ++i) {
#pragma unroll
    for (int j = 0; j < 4; ++j) {
      const int col = n0 + j * 16 + ccol;
      const float bv = bias[col];
      float hwv = 1.f;
      if constexpr (EPI == 2) hwv = hw[col >> 6];
#pragma unroll
      for (int r = 0; r < 4; ++r) {
        const int row = m0 + i * 16 + crow + r;
        const size_t idx = (size_t)row * N + col;
        float x = acc[i][j][r] + bv;
        if constexpr (EPI == 0) outB[idx] = f2b(tanhf(x));
        else if constexpr (EPI == 1) outB[idx] = f2b(x);
        else if constexpr (EPI == 2) outB[idx] = f2b(hwv * (x + b2f(addB[idx])));
        else if constexpr (EPI == 3) {
          float gl = 0.5f * x * (1.f + erff(x * 0.70710678118654752f));
          outB[idx] = f2b(gl);
        } else if constexpr (EPI == 4) outB[idx] = f2b(x + b2f(addB[idx]));
        else outF[idx] = x;
      }
    }
  }
}

// ---------------- chunked affine scan: h_t = a_t*h_{t-1} + b_t ----------------
__global__ __launch_bounds__(256) void scan_p1(const unsigned short* __restrict__ a,
                                               const unsigned short* __restrict__ bsrc,
                                               float* __restrict__ agA,
                                               float* __restrict__ agB) {
  const int idx = blockIdx.x;
  const int cg = idx & 3, ch = (idx >> 2) & (NCH - 1), bb = idx >> 8;
  const int c = cg * 256 + threadIdx.x;
  const size_t base = ((size_t)bb * LL + (size_t)ch * TCH) * HID + c;
  float A = 1.f, Bg = 0.f;
#pragma unroll 4
  for (int t = 0; t < TCH; ++t) {
    float at = b2f(a[base + (size_t)t * HID]);
    float bt = b2f(bsrc[base + (size_t)t * HID]);
    Bg = fmaf(at, Bg, bt);
    A *= at;
  }
  const size_t o = ((size_t)bb * NCH + ch) * HID + c;
  agA[o] = A;
  agB[o] = Bg;
}

__global__ __launch_bounds__(256) void scan_p2(const float* __restrict__ agA,
                                               const float* __restrict__ agB,
                                               float* __restrict__ pre) {
  const int gid = blockIdx.x * 256 + threadIdx.x;  // 4096 = BB*HID
  const int bb = gid >> 10, c = gid & 1023;
  float h = 0.f;
  for (int ch = 0; ch < NCH; ++ch) {
    const size_t o = ((size_t)bb * NCH + ch) * HID + c;
    pre[o] = h;
    h = fmaf(agA[o], h, agB[o]);
  }
}

__global__ __launch_bounds__(256) void scan_p3(const unsigned short* __restrict__ a,
                                               const unsigned short* __restrict__ bsrc,
                                               const float* __restrict__ pre,
                                               unsigned short* __restrict__ hout) {
  const int idx = blockIdx.x;
  const int cg = idx & 3, ch = (idx >> 2) & (NCH - 1), bb = idx >> 8;
  const int c = cg * 256 + threadIdx.x;
  const size_t base = ((size_t)bb * LL + (size_t)ch * TCH) * HID + c;
  float h = pre[((size_t)bb * NCH + ch) * HID + c];
#pragma unroll 4
  for (int t = 0; t < TCH; ++t) {
    float at = b2f(a[base + (size_t)t * HID]);
    float bt = b2f(bsrc[base + (size_t)t * HID]);
    h = fmaf(at, h, bt);
    hout[base + (size_t)t * HID] = f2b(h);
  }
}

// ---------------- u = z + layernorm(z) -> bf16 ----------------
__global__ __launch_bounds__(256) void ln_kernel(const unsigned short* __restrict__ z,
                                                 const float* __restrict__ gam,
                                                 const float* __restrict__ bet,
                                                 unsigned short* __restrict__ u) {
  const int wave = threadIdx.x >> 6, lane = threadIdx.x & 63;
  const int row = blockIdx.x * 4 + wave;
  const unsigned short* zr = z + (size_t)row * HID + lane * 16;
  short8 z0 = *(const short8*)zr;
  short8 z1 = *(const short8*)(zr + 8);
  float x[16];
#pragma unroll
  for (int e = 0; e < 8; ++e) {
    x[e]     = b2f((unsigned short)z0[e]);
    x[8 + e] = b2f((unsigned short)z1[e]);
  }
  float s = 0.f, s2 = 0.f;
#pragma unroll
  for (int e = 0; e < 16; ++e) { s += x[e]; s2 += x[e] * x[e]; }
#pragma unroll
  for (int off = 32; off > 0; off >>= 1) {
    s += __shfl_xor(s, off, 64);
    s2 += __shfl_xor(s2, off, 64);
  }
  const float mu = s * (1.f / 1024.f);
  const float var = s2 * (1.f / 1024.f) - mu * mu;
  const float rs = rsqrtf(var + 1e-5f);
  const float* gp = gam + lane * 16;
  const float* bp = bet + lane * 16;
  short8 o0, o1;
#pragma unroll
  for (int e = 0; e < 8; ++e) {
    float v0 = x[e]     + (x[e]     - mu) * rs * gp[e]     + bp[e];
    float v1 = x[8 + e] + (x[8 + e] - mu) * rs * gp[8 + e] + bp[8 + e];
    o0[e] = (short)f2b(v0);
    o1[e] = (short)f2b(v1);
  }
  unsigned short* ur = u + (size_t)row * HID + lane * 16;
  *(short8*)ur = o0;
  *(short8*)(ur + 8) = o1;
}

// ---------------- launch ----------------
extern "C" void kernel_launch(void* const* d_in, const int* in_sizes, int n_in,
                              void* d_out, int out_size, void* d_ws, size_t ws_size,
                              hipStream_t stream) {
  if (ws_size < WS_NEEDED) return;  // diagnostic guard: clean fail instead of fault

  const float* emb   = (const float*)d_in[0];
  const float* Wa_w  = (const float*)d_in[1];
  const float* Wa_b  = (const float*)d_in[2];
  const float* Wb_w  = (const float*)d_in[3];
  const float* Wb_b  = (const float*)d_in[4];
  const float* Wo_w  = (const float*)d_in[5];
  const float* Wo_b  = (const float*)d_in[6];
  const float* C_w   = (const float*)d_in[7];
  const float* C_b   = (const float*)d_in[8];
  const float* ln_g  = (const float*)d_in[9];
  const float* ln_b  = (const float*)d_in[10];
  const float* f1_w  = (const float*)d_in[11];
  const float* f1_b  = (const float*)d_in[12];
  const float* f2_w  = (const float*)d_in[13];
  const float* f2_b  = (const float*)d_in[14];
  const float* p_w   = (const float*)d_in[15];
  const float* p_b   = (const float*)d_in[16];
  const float* headw = (const float*)d_in[17];

  char* ws = (char*)d_ws;
  unsigned short* bfp  = (unsigned short*)ws;
  unsigned short* uB   = (unsigned short*)(ws + OFF_U);
  unsigned short* aB   = (unsigned short*)(ws + OFF_AZ);
  unsigned short* zB   = aB;                            // a dead after scan
  unsigned short* ffnB = aB;                            // z,w dead after LN/zGEMM (64MB span)
  unsigned short* wB   = (unsigned short*)(ws + OFF_W2);
  unsigned short* hB   = (unsigned short*)(ws + OFF_H2);
  unsigned short* vB   = hB;                            // h dead after zGEMM
  unsigned short* bA   = (unsigned short*)(ws + OFF_B2);
  float* agA = (float*)(ws + OFF_AGG);
  float* agB = agA + AG_ELEMS;
  float* pre = agB + AG_ELEMS;

  convert_all<<<2048, 256, 0, stream>>>(emb, Wa_w, Wb_w, Wo_w, C_w, f1_w, f2_w, p_w, bfp);

  dim3 g8(128, 8), h32(64, 32), h8(64, 8);
  gemm_bt<0><<<g8, 256, 0, stream>>>(bfp + ELN_EMB, bfp + ELN_WA, 1024, 1024, Wa_b, nullptr, nullptr, nullptr, aB);
  gemm_bt<1><<<g8, 256, 0, stream>>>(bfp + ELN_EMB, bfp + ELN_WB, 1024, 1024, Wb_b, nullptr, nullptr, nullptr, bA);
  gemm_bt<1><<<g8, 256, 0, stream>>>(bfp + ELN_EMB, bfp + ELN_WO, 1024, 1024, Wo_b, nullptr, nullptr, nullptr, wB);

  scan_p1<<<BB * NCH * 4, 256, 0, stream>>>(aB, bA, agA, agB);
  scan_p2<<<16, 256, 0, stream>>>(agA, agB, pre);
  scan_p3<<<BB * NCH * 4, 256, 0, stream>>>(aB, bA, pre, hB);

  gemm_bt<2><<<g8, 256, 0, stream>>>(hB, bfp + ELN_CW, 1024, 1024, C_b, wB, headw, nullptr, zB);
  ln_kernel<<<4096, 256, 0, stream>>>(zB, ln_g, ln_b, uB);

  // FFN in two M-halves so ffn fits in 64MB (regions AZ+W2)
  for (int half = 0; half < 2; ++half) {
    const size_t ro = (size_t)half * 8192 * 1024;
    gemm_bt<3><<<h32, 256, 0, stream>>>(uB + ro, bfp + ELN_F1, 1024, 4096, f1_b, nullptr, nullptr, nullptr, ffnB);
    gemm_bt<4><<<h8, 256, 0, stream>>>(ffnB, bfp + ELN_F2, 4096, 1024, f2_b, uB + ro, nullptr, nullptr, vB + ro);
  }

  gemm_bt<5><<<g8, 256, 0, stream>>>(vB, bfp + ELN_PW, 1024, 1024, p_b, nullptr, nullptr, (float*)d_out, nullptr);
}